// Round 5
// baseline (395.705 us; speedup 1.0000x reference)
//
#include <hip/hip_runtime.h>
#include <math.h>

#define D_MODEL   512
#define MAX_PL    32
#define TGT       4
#define NTHREADS  256
#define HSTRIDE   65

// ================= Kernel P: patch-length classifier =================
// Block: 256 threads, 64 tiles. Writes pred (0/1/2) per tile to workspace.
#define P_TILES 64
__global__ __launch_bounds__(NTHREADS)
void ape_preds(const float* __restrict__ x,
               const float* __restrict__ w1, const float* __restrict__ b1,
               const float* __restrict__ w2, const float* __restrict__ b2,
               int* __restrict__ preds_out)
{
    __shared__ float xs[P_TILES * MAX_PL];     // 8 KB
    __shared__ float hbuf[P_TILES * HSTRIDE];  // 16.6 KB, padded stride
    __shared__ float lbuf[P_TILES * 3];

    const int t = threadIdx.x;
    const long long tile0 = (long long)blockIdx.x * P_TILES;

    {
        const float* xb = x + tile0 * MAX_PL;
        #pragma unroll
        for (int i = 0; i < 8; ++i)
            xs[t + i * 256] = xb[t + i * 256];
    }
    __syncthreads();

    {
        const int hidx = t & 63;
        float wreg[MAX_PL] __attribute__((aligned(16)));
        {
            const float4* w1q = (const float4*)(w1 + hidx * MAX_PL);
            float4* wq = (float4*)wreg;
            #pragma unroll
            for (int i = 0; i < 8; ++i) wq[i] = w1q[i];
        }
        const float bb = b1[hidx];
        const int gbase = t >> 6;
        #pragma unroll
        for (int gg = 0; gg < 16; ++gg) {
            const int g = gbase + gg * 4;
            float acc = 0.f;
            #pragma unroll
            for (int p = 0; p < MAX_PL; ++p)
                acc = fmaf(wreg[p], xs[g * MAX_PL + p], acc);
            hbuf[g * HSTRIDE + hidx] = fmaxf(acc + bb, 0.f);
        }
    }
    __syncthreads();

    if (t < 192) {
        const int g = t / 3, e = t - g * 3;
        const float* hg = hbuf + g * HSTRIDE;
        const float* w2r = w2 + e * 64;
        float acc = 0.f;
        #pragma unroll 8
        for (int h = 0; h < 64; ++h) acc = fmaf(w2r[h], hg[h], acc);
        lbuf[g * 3 + e] = acc + b2[e];
    }
    __syncthreads();

    // argmax (first-max-on-ties, matching jnp.argmax)
    if (t < P_TILES) {
        const float l0 = lbuf[t * 3], l1 = lbuf[t * 3 + 1], l2 = lbuf[t * 3 + 2];
        int bi = 0; float best = l0;
        if (l1 > best) { best = l1; bi = 1; }
        if (l2 > best) { bi = 2; }
        preds_out[tile0 + t] = bi;
    }
}

// ================= Kernel E: embedding + PE + store =================
// One block per tile-group (32 tiles = one full n, r=0..31). Thread t owns
// the dim PAIR (2t, 2t+1): float2 nontemporal stores (8B/lane, 512B/wave),
// table rows for both dims in registers (112 floats), PE state is the
// natural (sin,cos) pair -- no sign trick. ~155 VGPR -> 3 waves/SIMD
// (launch_bounds(256,3) caps at 170: no spill pressure).
#define G_TILES 32
__global__ __launch_bounds__(NTHREADS, 3)
void ape_embed(const float* __restrict__ x,
               const int* __restrict__ preds_in,
               const float* __restrict__ we0, const float* __restrict__ we1,
               const float* __restrict__ we2,
               float* __restrict__ out)
{
    __shared__ float xs[G_TILES * MAX_PL];   // 4 KB
    __shared__ int   sp[G_TILES];

    const int t = threadIdx.x;
    const long long tile0 = (long long)blockIdx.x * G_TILES;
    const int d0 = t << 1;

    // ---- preload table rows for dims d0, d0+1 (contiguous rows) ----
    float r0[2][8]  __attribute__((aligned(16)));
    float r1[2][16] __attribute__((aligned(16)));
    float r2[2][32] __attribute__((aligned(16)));
    {
        const float4* s0 = (const float4*)(we0 + (size_t)d0 * 8);
        #pragma unroll
        for (int i = 0; i < 4; ++i) ((float4*)&r0[0][0])[i] = s0[i];
        const float4* s1 = (const float4*)(we1 + (size_t)d0 * 16);
        #pragma unroll
        for (int i = 0; i < 8; ++i) ((float4*)&r1[0][0])[i] = s1[i];
        const float4* s2 = (const float4*)(we2 + (size_t)d0 * 32);
        #pragma unroll
        for (int i = 0; i < 16; ++i) ((float4*)&r2[0][0])[i] = s2[i];
    }

    // ---- stage x + preds ----
    {
        const float* xb = x + tile0 * MAX_PL;
        #pragma unroll
        for (int i = 0; i < 4; ++i)
            xs[t + i * 256] = xb[t + i * 256];
        if (t < G_TILES) sp[t] = preds_in[tile0 + t];
    }

    // ---- PE: (sg,cg) = (sin,cos)(pos*freq); rotate by freq per position;
    //      seed (ss,cs) advanced by precomputed 32-pos rotation every 8 tiles
    const float freq = expf((float)d0 * -0.017988946f);  // -ln(10000)/512
    float s1r, c1r, s32r, c32r;
    sincosf(freq, &s1r, &c1r);
    sincosf(32.0f * freq, &s32r, &c32r);
    float ss = 0.f, cs = 1.f;   // seed at position 0
    float sg = 0.f, cg = 1.f;

    __syncthreads();

    for (int g = 0; g < G_TILES; ++g) {
        if ((g & 7) == 0 && g != 0) {
            // advance seed exactly 32 positions; re-seed rotation state
            const float ns = fmaf(ss, c32r,  cs * s32r);
            const float nc = fmaf(cs, c32r, -ss * s32r);
            ss = ns; cs = nc;
            sg = ss; cg = cs;
        }
        const int pred = sp[g];
        float* obase = out + (tile0 + g) * (TGT * D_MODEL) + d0;
        const float4* xg4 = (const float4*)(xs + g * MAX_PL);

        float v[TGT][2];
        if (pred == 0) {            // pl=8: 4 distinct patches
            #pragma unroll
            for (int k = 0; k < 4; ++k) {
                float xq8[8] __attribute__((aligned(16)));
                ((float4*)xq8)[0] = xg4[2 * k];
                ((float4*)xq8)[1] = xg4[2 * k + 1];
                float a0 = 0.f, a1 = 0.f;
                #pragma unroll
                for (int j = 0; j < 8; ++j) {
                    a0 = fmaf(r0[0][j], xq8[j], a0);
                    a1 = fmaf(r0[1][j], xq8[j], a1);
                }
                v[k][0] = a0; v[k][1] = a1;
            }
        } else if (pred == 1) {     // pl=16: repeat idx [0,0,0,1]
            float bt[2][2];
            #pragma unroll
            for (int kp = 0; kp < 2; ++kp) {
                float a0 = 0.f, a1 = 0.f;
                #pragma unroll
                for (int c = 0; c < 2; ++c) {
                    float xq8[8] __attribute__((aligned(16)));
                    ((float4*)xq8)[0] = xg4[kp * 4 + 2 * c];
                    ((float4*)xq8)[1] = xg4[kp * 4 + 2 * c + 1];
                    #pragma unroll
                    for (int j = 0; j < 8; ++j) {
                        a0 = fmaf(r1[0][c * 8 + j], xq8[j], a0);
                        a1 = fmaf(r1[1][c * 8 + j], xq8[j], a1);
                    }
                }
                bt[kp][0] = a0; bt[kp][1] = a1;
            }
            v[0][0] = bt[0][0]; v[0][1] = bt[0][1];
            v[1][0] = bt[0][0]; v[1][1] = bt[0][1];
            v[2][0] = bt[0][0]; v[2][1] = bt[0][1];
            v[3][0] = bt[1][0]; v[3][1] = bt[1][1];
        } else {                    // pl=32: one patch, repeated 4x
            float a0 = 0.f, a1 = 0.f;
            #pragma unroll
            for (int c = 0; c < 4; ++c) {
                float xq8[8] __attribute__((aligned(16)));
                ((float4*)xq8)[0] = xg4[2 * c];
                ((float4*)xq8)[1] = xg4[2 * c + 1];
                #pragma unroll
                for (int j = 0; j < 8; ++j) {
                    a0 = fmaf(r2[0][c * 8 + j], xq8[j], a0);
                    a1 = fmaf(r2[1][c * 8 + j], xq8[j], a1);
                }
            }
            #pragma unroll
            for (int k = 0; k < 4; ++k) { v[k][0] = a0; v[k][1] = a1; }
        }

        // add PE pair, rotate per position, float2 nontemporal stores
        #pragma unroll
        for (int k = 0; k < 4; ++k) {
            float2 o;
            o.x = v[k][0] + sg;   // even dim: sin
            o.y = v[k][1] + cg;   // odd dim: cos
            __builtin_nontemporal_store(*(const unsigned long long*)&o,
                                        (unsigned long long*)(obase + k * D_MODEL));
            const float ns = fmaf(sg, c1r,  cg * s1r);
            const float nc = fmaf(cg, c1r, -sg * s1r);
            sg = ns; cg = nc;
        }
    }
}

// Second tuple output: the scalar C (=21) appended after x_patch.
__global__ void ape_tail(float* p, int n) {
    int i = blockIdx.x * blockDim.x + threadIdx.x;
    if (i < n) p[i] = 21.0f;
}

extern "C" void kernel_launch(void* const* d_in, const int* in_sizes, int n_in,
                              void* d_out, int out_size, void* d_ws, size_t ws_size,
                              hipStream_t stream)
{
    const float* x   = (const float*)d_in[0];
    const float* w1  = (const float*)d_in[1];
    const float* b1  = (const float*)d_in[2];
    const float* w2  = (const float*)d_in[3];
    const float* b2  = (const float*)d_in[4];
    const float* we0 = (const float*)d_in[5];
    const float* we1 = (const float*)d_in[6];
    const float* we2 = (const float*)d_in[7];
    float* out = (float*)d_out;
    int* preds = (int*)d_ws;                                // 43008 ints = 172 KB

    const long long NR = (long long)in_sizes[0] / MAX_PL;   // B*C*R = 43008

    ape_preds<<<(int)(NR / P_TILES), NTHREADS, 0, stream>>>(x, w1, b1, w2, b2, preds);

    const int nblocks = (int)(NR / G_TILES);                // 1344
    ape_embed<<<nblocks, NTHREADS, 0, stream>>>(x, preds, we0, we1, we2, out);

    const long long main_elems = NR * (long long)(TGT * D_MODEL);
    if ((long long)out_size > main_elems) {
        const int tail = (int)((long long)out_size - main_elems);
        ape_tail<<<(tail + 63) / 64, 64, 0, stream>>>(out + main_elems, tail);
    }
}

// Round 7
// 390.634 us; speedup vs baseline: 1.0130x; 1.0130x over previous
//
#include <hip/hip_runtime.h>
#include <math.h>

#define D_MODEL   512
#define MAX_PL    32
#define TGT       4
#define NTHREADS  256
#define HSTRIDE   65

// ================= Kernel P: patch-length classifier =================
// Block: 256 threads, 64 tiles. Writes pred (0/1/2) per tile to workspace.
#define P_TILES 64
__global__ __launch_bounds__(NTHREADS)
void ape_preds(const float* __restrict__ x,
               const float* __restrict__ w1, const float* __restrict__ b1,
               const float* __restrict__ w2, const float* __restrict__ b2,
               int* __restrict__ preds_out)
{
    __shared__ float xs[P_TILES * MAX_PL];     // 8 KB
    __shared__ float hbuf[P_TILES * HSTRIDE];  // 16.6 KB, padded stride
    __shared__ float lbuf[P_TILES * 3];

    const int t = threadIdx.x;
    const long long tile0 = (long long)blockIdx.x * P_TILES;

    {
        const float* xb = x + tile0 * MAX_PL;
        #pragma unroll
        for (int i = 0; i < 8; ++i)
            xs[t + i * 256] = xb[t + i * 256];
    }
    __syncthreads();

    {
        const int hidx = t & 63;
        float wreg[MAX_PL] __attribute__((aligned(16)));
        {
            const float4* w1q = (const float4*)(w1 + hidx * MAX_PL);
            float4* wq = (float4*)wreg;
            #pragma unroll
            for (int i = 0; i < 8; ++i) wq[i] = w1q[i];
        }
        const float bb = b1[hidx];
        const int gbase = t >> 6;
        #pragma unroll
        for (int gg = 0; gg < 16; ++gg) {
            const int g = gbase + gg * 4;
            float acc = 0.f;
            #pragma unroll
            for (int p = 0; p < MAX_PL; ++p)
                acc = fmaf(wreg[p], xs[g * MAX_PL + p], acc);
            hbuf[g * HSTRIDE + hidx] = fmaxf(acc + bb, 0.f);
        }
    }
    __syncthreads();

    if (t < 192) {
        const int g = t / 3, e = t - g * 3;
        const float* hg = hbuf + g * HSTRIDE;
        const float* w2r = w2 + e * 64;
        float acc = 0.f;
        #pragma unroll 8
        for (int h = 0; h < 64; ++h) acc = fmaf(w2r[h], hg[h], acc);
        lbuf[g * 3 + e] = acc + b2[e];
    }
    __syncthreads();

    // argmax (first-max-on-ties, matching jnp.argmax)
    if (t < P_TILES) {
        const float l0 = lbuf[t * 3], l1 = lbuf[t * 3 + 1], l2 = lbuf[t * 3 + 2];
        int bi = 0; float best = l0;
        if (l1 > best) { best = l1; bi = 1; }
        if (l2 > best) { bi = 2; }
        preds_out[tile0 + t] = bi;
    }
}

// ================= Kernel E: embedding + PE + store =================
// Two blocks per tile-group (group = bid>>1, half = bid&1); half h covers
// dims [h*256, h*256+255], one dim per thread (R4 structure: proven best).
// NO LDS, NO barriers: the x-tile and pred are block-uniform -> read via
// uniform addresses (compiler emits s_load / broadcast loads). Per-thread
// state: 56 table floats + PE + misc ~ 90 VGPR -> 5-6 waves/SIMD.
#define G_TILES 32
__global__ __launch_bounds__(NTHREADS, 4)
void ape_embed(const float* __restrict__ x,
               const int* __restrict__ preds_in,
               const float* __restrict__ we0, const float* __restrict__ we1,
               const float* __restrict__ we2,
               float* __restrict__ out)
{
    const int t     = threadIdx.x;
    const int group = blockIdx.x >> 1;
    const int half  = blockIdx.x & 1;
    const long long tile0 = (long long)group * G_TILES;
    const float4* __restrict__ xb4 = (const float4*)(x + tile0 * MAX_PL); // uniform

    // preload this thread's w_emb row (dim d) for all 3 tables (56 floats)
    const int d = half * 256 + t;
    float r0[8]  __attribute__((aligned(16)));
    float r1[16] __attribute__((aligned(16)));
    float r2[32] __attribute__((aligned(16)));
    {
        const float4* s0 = (const float4*)(we0 + (size_t)d * 8);
        ((float4*)r0)[0] = s0[0]; ((float4*)r0)[1] = s0[1];
        const float4* s1 = (const float4*)(we1 + (size_t)d * 16);
        #pragma unroll
        for (int i = 0; i < 4; ++i) ((float4*)r1)[i] = s1[i];
        const float4* s2 = (const float4*)(we2 + (size_t)d * 32);
        #pragma unroll
        for (int i = 0; i < 8; ++i) ((float4*)r2)[i] = s2[i];
    }

    // PE state: add sin(pos*freq) for even d, cos for odd d.
    // (pg,qg) rotated by freq per position; seed (ps,qs) advanced by a
    // precomputed 32-position rotation every 8 tiles (drift <= 36 steps).
    const float freq = expf((float)(d & ~1) * -0.017988946f);  // -ln(1e4)/512
    float s1r, c1r, s32r, c32r;
    sincosf(freq, &s1r, &c1r);
    sincosf(32.0f * freq, &s32r, &c32r);
    const float sgn  = (d & 1) ? -1.f : 1.f;
    const float s1l  = sgn * s1r;
    const float s32l = sgn * s32r;
    float ps = (d & 1) ? 1.f : 0.f;   // position 0: sin0=0 / cos0=1
    float qs = (d & 1) ? 0.f : 1.f;
    float pg = ps, qg = qs;

    for (int g = 0; g < G_TILES; ++g) {
        if ((g & 7) == 0 && g != 0) {
            // advance seed exactly one 32-position step; re-seed inner state
            const float np = fmaf(ps, c32r,  qs * s32l);
            const float nq = fmaf(qs, c32r, -ps * s32l);
            ps = np; qs = nq;
            pg = ps; qg = qs;
        }
        const int pred = preds_in[tile0 + g];       // uniform scalar load
        float* obase = out + (tile0 + g) * (TGT * D_MODEL) + d;
        const float4* xg4 = xb4 + g * 8;            // uniform base

        float v[TGT];
        if (pred == 0) {            // pl=8: 4 distinct patches
            #pragma unroll
            for (int k = 0; k < 4; ++k) {
                float xq8[8] __attribute__((aligned(16)));
                ((float4*)xq8)[0] = xg4[2 * k];
                ((float4*)xq8)[1] = xg4[2 * k + 1];
                float a = 0.f, b = 0.f;
                #pragma unroll
                for (int j = 0; j < 4; ++j) {
                    a = fmaf(r0[j],     xq8[j],     a);
                    b = fmaf(r0[j + 4], xq8[j + 4], b);
                }
                v[k] = a + b;
            }
        } else if (pred == 1) {     // pl=16: repeat idx [0,0,0,1]
            float bt[2];
            #pragma unroll
            for (int kp = 0; kp < 2; ++kp) {
                float a = 0.f, b = 0.f;
                #pragma unroll
                for (int c = 0; c < 2; ++c) {
                    float xq8[8] __attribute__((aligned(16)));
                    ((float4*)xq8)[0] = xg4[kp * 4 + 2 * c];
                    ((float4*)xq8)[1] = xg4[kp * 4 + 2 * c + 1];
                    #pragma unroll
                    for (int j = 0; j < 4; ++j) {
                        a = fmaf(r1[c * 8 + j],     xq8[j],     a);
                        b = fmaf(r1[c * 8 + j + 4], xq8[j + 4], b);
                    }
                }
                bt[kp] = a + b;
            }
            v[0] = bt[0]; v[1] = bt[0]; v[2] = bt[0]; v[3] = bt[1];
        } else {                    // pl=32: one patch, repeated 4x
            float a = 0.f, b = 0.f;
            #pragma unroll
            for (int c = 0; c < 4; ++c) {
                float xq8[8] __attribute__((aligned(16)));
                ((float4*)xq8)[0] = xg4[2 * c];
                ((float4*)xq8)[1] = xg4[2 * c + 1];
                #pragma unroll
                for (int j = 0; j < 4; ++j) {
                    a = fmaf(r2[c * 8 + j],     xq8[j],     a);
                    b = fmaf(r2[c * 8 + j + 4], xq8[j + 4], b);
                }
            }
            const float av = a + b;
            #pragma unroll
            for (int k = 0; k < 4; ++k) v[k] = av;
        }

        // add PE, rotate per position, nontemporal coalesced stores
        #pragma unroll
        for (int k = 0; k < 4; ++k) {
            __builtin_nontemporal_store(v[k] + pg, obase + k * D_MODEL);
            const float np = fmaf(pg, c1r,  qg * s1l);
            const float nq = fmaf(qg, c1r, -pg * s1l);
            pg = np; qg = nq;
        }
    }
}

// Second tuple output: the scalar C (=21) appended after x_patch.
__global__ void ape_tail(float* p, int n) {
    int i = blockIdx.x * blockDim.x + threadIdx.x;
    if (i < n) p[i] = 21.0f;
}

extern "C" void kernel_launch(void* const* d_in, const int* in_sizes, int n_in,
                              void* d_out, int out_size, void* d_ws, size_t ws_size,
                              hipStream_t stream)
{
    const float* x   = (const float*)d_in[0];
    const float* w1  = (const float*)d_in[1];
    const float* b1  = (const float*)d_in[2];
    const float* w2  = (const float*)d_in[3];
    const float* b2  = (const float*)d_in[4];
    const float* we0 = (const float*)d_in[5];
    const float* we1 = (const float*)d_in[6];
    const float* we2 = (const float*)d_in[7];
    float* out = (float*)d_out;
    int* preds = (int*)d_ws;                                // 43008 ints = 172 KB

    const long long NR = (long long)in_sizes[0] / MAX_PL;   // B*C*R = 43008

    ape_preds<<<(int)(NR / P_TILES), NTHREADS, 0, stream>>>(x, w1, b1, w2, b2, preds);

    const int nblocks = (int)(NR / G_TILES) * 2;            // 2688 half-blocks
    ape_embed<<<nblocks, NTHREADS, 0, stream>>>(x, preds, we0, we1, we2, out);

    const long long main_elems = NR * (long long)(TGT * D_MODEL);
    if ((long long)out_size > main_elems) {
        const int tail = (int)((long long)out_size - main_elems);
        ape_tail<<<(tail + 63) / 64, 64, 0, stream>>>(out + main_elems, tail);
    }
}

// Round 8
// 390.321 us; speedup vs baseline: 1.0138x; 1.0008x over previous
//
#include <hip/hip_runtime.h>
#include <math.h>

#define D_MODEL   512
#define MAX_PL    32
#define TGT       4
#define NTHREADS  256
#define HSTRIDE   65

// ================= Kernel P: patch-length classifier =================
// Block: 256 threads, 64 tiles. Writes pred (0/1/2) per tile to workspace.
#define P_TILES 64
__global__ __launch_bounds__(NTHREADS)
void ape_preds(const float* __restrict__ x,
               const float* __restrict__ w1, const float* __restrict__ b1,
               const float* __restrict__ w2, const float* __restrict__ b2,
               int* __restrict__ preds_out)
{
    __shared__ float xs[P_TILES * MAX_PL];     // 8 KB
    __shared__ float hbuf[P_TILES * HSTRIDE];  // 16.6 KB, padded stride
    __shared__ float lbuf[P_TILES * 3];

    const int t = threadIdx.x;
    const long long tile0 = (long long)blockIdx.x * P_TILES;

    {
        const float* xb = x + tile0 * MAX_PL;
        #pragma unroll
        for (int i = 0; i < 8; ++i)
            xs[t + i * 256] = xb[t + i * 256];
    }
    __syncthreads();

    {
        const int hidx = t & 63;
        float wreg[MAX_PL] __attribute__((aligned(16)));
        {
            const float4* w1q = (const float4*)(w1 + hidx * MAX_PL);
            float4* wq = (float4*)wreg;
            #pragma unroll
            for (int i = 0; i < 8; ++i) wq[i] = w1q[i];
        }
        const float bb = b1[hidx];
        const int gbase = t >> 6;
        #pragma unroll
        for (int gg = 0; gg < 16; ++gg) {
            const int g = gbase + gg * 4;
            float acc = 0.f;
            #pragma unroll
            for (int p = 0; p < MAX_PL; ++p)
                acc = fmaf(wreg[p], xs[g * MAX_PL + p], acc);
            hbuf[g * HSTRIDE + hidx] = fmaxf(acc + bb, 0.f);
        }
    }
    __syncthreads();

    if (t < 192) {
        const int g = t / 3, e = t - g * 3;
        const float* hg = hbuf + g * HSTRIDE;
        const float* w2r = w2 + e * 64;
        float acc = 0.f;
        #pragma unroll 8
        for (int h = 0; h < 64; ++h) acc = fmaf(w2r[h], hg[h], acc);
        lbuf[g * 3 + e] = acc + b2[e];
    }
    __syncthreads();

    // argmax (first-max-on-ties, matching jnp.argmax)
    if (t < P_TILES) {
        const float l0 = lbuf[t * 3], l1 = lbuf[t * 3 + 1], l2 = lbuf[t * 3 + 2];
        int bi = 0; float best = l0;
        if (l1 > best) { best = l1; bi = 1; }
        if (l2 > best) { bi = 2; }
        preds_out[tile0 + t] = bi;
    }
}

// ================= Kernel E: embedding + PE + store =================
// Identical to the measured-best 379.9us version (split kernels, half-blocks,
// 1 dim/thread, LDS-staged x+preds, one barrier) EXCEPT: plain stores instead
// of __builtin_nontemporal_store. Theory: NT bypasses L2 -> fine-grained
// strided HBM writes at ~2.4 TB/s; plain stores let L2 aggregate full lines
// (the 6.2 TB/s fill path). Output has no reuse, so L2 routing costs nothing.
#define G_TILES 32
__global__ __launch_bounds__(NTHREADS, 3)
void ape_embed(const float* __restrict__ x,
               const int* __restrict__ preds_in,
               const float* __restrict__ we0, const float* __restrict__ we1,
               const float* __restrict__ we2,
               float* __restrict__ out)
{
    __shared__ float xs[G_TILES * MAX_PL];   // 4 KB
    __shared__ int   sp[G_TILES];

    const int t     = threadIdx.x;
    const int group = blockIdx.x >> 1;
    const int half  = blockIdx.x & 1;
    const long long tile0 = (long long)group * G_TILES;

    // stage x + preds
    {
        const float* xb = x + tile0 * MAX_PL;
        #pragma unroll
        for (int i = 0; i < 4; ++i)
            xs[t + i * 256] = xb[t + i * 256];
        if (t < G_TILES) sp[t] = preds_in[tile0 + t];
    }

    // preload this thread's w_emb row (dim d) for all 3 tables (56 floats)
    const int d = half * 256 + t;
    float r0[8]  __attribute__((aligned(16)));
    float r1[16] __attribute__((aligned(16)));
    float r2[32] __attribute__((aligned(16)));
    {
        const float4* s0 = (const float4*)(we0 + (size_t)d * 8);
        ((float4*)r0)[0] = s0[0]; ((float4*)r0)[1] = s0[1];
        const float4* s1 = (const float4*)(we1 + (size_t)d * 16);
        #pragma unroll
        for (int i = 0; i < 4; ++i) ((float4*)r1)[i] = s1[i];
        const float4* s2 = (const float4*)(we2 + (size_t)d * 32);
        #pragma unroll
        for (int i = 0; i < 8; ++i) ((float4*)r2)[i] = s2[i];
    }

    // PE state: add sin(pos*freq) for even d, cos for odd d.
    // (pg,qg) rotated by freq per position; seed (ps,qs) advanced by a
    // precomputed 32-position rotation every 8 tiles (drift <= 36 steps).
    const float freq = expf((float)(d & ~1) * -0.017988946f);  // -ln(1e4)/512
    float s1r, c1r, s32r, c32r;
    sincosf(freq, &s1r, &c1r);
    sincosf(32.0f * freq, &s32r, &c32r);
    const float sgn  = (d & 1) ? -1.f : 1.f;
    const float s1l  = sgn * s1r;
    const float s32l = sgn * s32r;
    float ps = (d & 1) ? 1.f : 0.f;   // position 0: sin0=0 / cos0=1
    float qs = (d & 1) ? 0.f : 1.f;
    float pg = ps, qg = qs;

    __syncthreads();

    for (int g = 0; g < G_TILES; ++g) {
        if ((g & 7) == 0 && g != 0) {
            // advance seed exactly one 32-position step; re-seed inner state
            const float np = fmaf(ps, c32r,  qs * s32l);
            const float nq = fmaf(qs, c32r, -ps * s32l);
            ps = np; qs = nq;
            pg = ps; qg = qs;
        }
        const int pred = sp[g];
        float* obase = out + (tile0 + g) * (TGT * D_MODEL) + d;
        const float4* xg4 = (const float4*)(xs + g * MAX_PL);

        float v[TGT];
        if (pred == 0) {            // pl=8: 4 distinct patches
            #pragma unroll
            for (int k = 0; k < 4; ++k) {
                float xq8[8] __attribute__((aligned(16)));
                ((float4*)xq8)[0] = xg4[2 * k];
                ((float4*)xq8)[1] = xg4[2 * k + 1];
                float a = 0.f, b = 0.f;
                #pragma unroll
                for (int j = 0; j < 4; ++j) {
                    a = fmaf(r0[j],     xq8[j],     a);
                    b = fmaf(r0[j + 4], xq8[j + 4], b);
                }
                v[k] = a + b;
            }
        } else if (pred == 1) {     // pl=16: repeat idx [0,0,0,1]
            float bt[2];
            #pragma unroll
            for (int kp = 0; kp < 2; ++kp) {
                float a = 0.f, b = 0.f;
                #pragma unroll
                for (int c = 0; c < 2; ++c) {
                    float xq8[8] __attribute__((aligned(16)));
                    ((float4*)xq8)[0] = xg4[kp * 4 + 2 * c];
                    ((float4*)xq8)[1] = xg4[kp * 4 + 2 * c + 1];
                    #pragma unroll
                    for (int j = 0; j < 4; ++j) {
                        a = fmaf(r1[c * 8 + j],     xq8[j],     a);
                        b = fmaf(r1[c * 8 + j + 4], xq8[j + 4], b);
                    }
                }
                bt[kp] = a + b;
            }
            v[0] = bt[0]; v[1] = bt[0]; v[2] = bt[0]; v[3] = bt[1];
        } else {                    // pl=32: one patch, repeated 4x
            float a = 0.f, b = 0.f;
            #pragma unroll
            for (int c = 0; c < 4; ++c) {
                float xq8[8] __attribute__((aligned(16)));
                ((float4*)xq8)[0] = xg4[2 * c];
                ((float4*)xq8)[1] = xg4[2 * c + 1];
                #pragma unroll
                for (int j = 0; j < 4; ++j) {
                    a = fmaf(r2[c * 8 + j],     xq8[j],     a);
                    b = fmaf(r2[c * 8 + j + 4], xq8[j + 4], b);
                }
            }
            const float av = a + b;
            #pragma unroll
            for (int k = 0; k < 4; ++k) v[k] = av;
        }

        // add PE, rotate per position; PLAIN stores (L2-aggregated writeback)
        #pragma unroll
        for (int k = 0; k < 4; ++k) {
            obase[k * D_MODEL] = v[k] + pg;
            const float np = fmaf(pg, c1r,  qg * s1l);
            const float nq = fmaf(qg, c1r, -pg * s1l);
            pg = np; qg = nq;
        }
    }
}

// Second tuple output: the scalar C (=21) appended after x_patch.
__global__ void ape_tail(float* p, int n) {
    int i = blockIdx.x * blockDim.x + threadIdx.x;
    if (i < n) p[i] = 21.0f;
}

extern "C" void kernel_launch(void* const* d_in, const int* in_sizes, int n_in,
                              void* d_out, int out_size, void* d_ws, size_t ws_size,
                              hipStream_t stream)
{
    const float* x   = (const float*)d_in[0];
    const float* w1  = (const float*)d_in[1];
    const float* b1  = (const float*)d_in[2];
    const float* w2  = (const float*)d_in[3];
    const float* b2  = (const float*)d_in[4];
    const float* we0 = (const float*)d_in[5];
    const float* we1 = (const float*)d_in[6];
    const float* we2 = (const float*)d_in[7];
    float* out = (float*)d_out;
    int* preds = (int*)d_ws;                                // 43008 ints = 172 KB

    const long long NR = (long long)in_sizes[0] / MAX_PL;   // B*C*R = 43008

    ape_preds<<<(int)(NR / P_TILES), NTHREADS, 0, stream>>>(x, w1, b1, w2, b2, preds);

    const int nblocks = (int)(NR / G_TILES) * 2;            // 2688 half-blocks
    ape_embed<<<nblocks, NTHREADS, 0, stream>>>(x, preds, we0, we1, we2, out);

    const long long main_elems = NR * (long long)(TGT * D_MODEL);
    if ((long long)out_size > main_elems) {
        const int tail = (int)((long long)out_size - main_elems);
        ape_tail<<<(tail + 63) / 64, 64, 0, stream>>>(out + main_elems, tail);
    }
}

// Round 9
// 381.608 us; speedup vs baseline: 1.0369x; 1.0228x over previous
//
#include <hip/hip_runtime.h>
#include <math.h>

#define D_MODEL   512
#define MAX_PL    32
#define TGT       4
#define NTHREADS  256
#define HSTRIDE   65

typedef float f32x16 __attribute__((ext_vector_type(16)));

// ================= Kernel P: patch-length classifier =================
// Block: 256 threads, 64 tiles. Writes pred (0/1/2) per tile to workspace.
#define P_TILES 64
__global__ __launch_bounds__(NTHREADS)
void ape_preds(const float* __restrict__ x,
               const float* __restrict__ w1, const float* __restrict__ b1,
               const float* __restrict__ w2, const float* __restrict__ b2,
               int* __restrict__ preds_out)
{
    __shared__ float xs[P_TILES * MAX_PL];     // 8 KB
    __shared__ float hbuf[P_TILES * HSTRIDE];  // 16.6 KB, padded stride
    __shared__ float lbuf[P_TILES * 3];

    const int t = threadIdx.x;
    const long long tile0 = (long long)blockIdx.x * P_TILES;

    {
        const float* xb = x + tile0 * MAX_PL;
        #pragma unroll
        for (int i = 0; i < 8; ++i)
            xs[t + i * 256] = xb[t + i * 256];
    }
    __syncthreads();

    {
        const int hidx = t & 63;
        float wreg[MAX_PL] __attribute__((aligned(16)));
        {
            const float4* w1q = (const float4*)(w1 + hidx * MAX_PL);
            float4* wq = (float4*)wreg;
            #pragma unroll
            for (int i = 0; i < 8; ++i) wq[i] = w1q[i];
        }
        const float bb = b1[hidx];
        const int gbase = t >> 6;
        #pragma unroll
        for (int gg = 0; gg < 16; ++gg) {
            const int g = gbase + gg * 4;
            float acc = 0.f;
            #pragma unroll
            for (int p = 0; p < MAX_PL; ++p)
                acc = fmaf(wreg[p], xs[g * MAX_PL + p], acc);
            hbuf[g * HSTRIDE + hidx] = fmaxf(acc + bb, 0.f);
        }
    }
    __syncthreads();

    if (t < 192) {
        const int g = t / 3, e = t - g * 3;
        const float* hg = hbuf + g * HSTRIDE;
        const float* w2r = w2 + e * 64;
        float acc = 0.f;
        #pragma unroll 8
        for (int h = 0; h < 64; ++h) acc = fmaf(w2r[h], hg[h], acc);
        lbuf[g * 3 + e] = acc + b2[e];
    }
    __syncthreads();

    // argmax (first-max-on-ties, matching jnp.argmax)
    if (t < P_TILES) {
        const float l0 = lbuf[t * 3], l1 = lbuf[t * 3 + 1], l2 = lbuf[t * 3 + 2];
        int bi = 0; float best = l0;
        if (l1 > best) { best = l1; bi = 1; }
        if (l2 > best) { bi = 2; }
        preds_out[tile0 + t] = bi;
    }
}

// ================= Kernel E: embedding + PE + store =================
// R4 structure (half-blocks, 1 dim/thread, NT stores) with ONE change:
// the block-uniform x-tile is loaded via inline-asm s_load_dwordx16 into
// SGPRs (scalar cache path) instead of per-lane LDS/vector loads. FMAs use
// the SGPR operand directly (v_fma v,v,s,v: 1 SGPR read, legal). Removes
// ALL per-lane x traffic from the LDS and vector-memory ports; no LDS, no
// barrier. ~85 VGPR -> 4 waves/SIMD.
#define G_TILES 32
// all loop indices into these are compile-time constants after unrolling
#define XAT(j) ((j) < 16 ? xlo[(j)] : xhi[(j) - 16])

__global__ __launch_bounds__(NTHREADS, 4)
void ape_embed(const float* __restrict__ x,
               const int* __restrict__ preds_in,
               const float* __restrict__ we0, const float* __restrict__ we1,
               const float* __restrict__ we2,
               float* __restrict__ out)
{
    const int t     = threadIdx.x;
    const int group = blockIdx.x >> 1;
    const int half  = blockIdx.x & 1;
    const long long tile0 = (long long)group * G_TILES;

    // preload this thread's w_emb row (dim d) for all 3 tables (56 floats)
    const int d = half * 256 + t;
    float r0[8]  __attribute__((aligned(16)));
    float r1[16] __attribute__((aligned(16)));
    float r2[32] __attribute__((aligned(16)));
    {
        const float4* s0 = (const float4*)(we0 + (size_t)d * 8);
        ((float4*)r0)[0] = s0[0]; ((float4*)r0)[1] = s0[1];
        const float4* s1 = (const float4*)(we1 + (size_t)d * 16);
        #pragma unroll
        for (int i = 0; i < 4; ++i) ((float4*)r1)[i] = s1[i];
        const float4* s2 = (const float4*)(we2 + (size_t)d * 32);
        #pragma unroll
        for (int i = 0; i < 8; ++i) ((float4*)r2)[i] = s2[i];
    }

    // PE state: add sin(pos*freq) for even d, cos for odd d.
    // (pg,qg) rotated by freq per position; seed (ps,qs) advanced by a
    // precomputed 32-position rotation every 8 tiles (drift <= 36 steps).
    const float freq = expf((float)(d & ~1) * -0.017988946f);  // -ln(1e4)/512
    float s1r, c1r, s32r, c32r;
    sincosf(freq, &s1r, &c1r);
    sincosf(32.0f * freq, &s32r, &c32r);
    const float sgn  = (d & 1) ? -1.f : 1.f;
    const float s1l  = sgn * s1r;
    const float s32l = sgn * s32r;
    float ps = (d & 1) ? 1.f : 0.f;   // position 0: sin0=0 / cos0=1
    float qs = (d & 1) ? 0.f : 1.f;
    float pg = ps, qg = qs;

    for (int g = 0; g < G_TILES; ++g) {
        if ((g & 7) == 0 && g != 0) {
            // advance seed exactly one 32-position step; re-seed inner state
            const float np = fmaf(ps, c32r,  qs * s32l);
            const float nq = fmaf(qs, c32r, -ps * s32l);
            ps = np; qs = nq;
            pg = ps; qg = qs;
        }
        const int pred = preds_in[tile0 + g];   // uniform scalar load
        float* obase = out + (tile0 + g) * (TGT * D_MODEL) + d;

        // ---- x-tile (block-uniform, read-only) -> SGPRs via s_load ----
        const float* xt = x + (tile0 + g) * MAX_PL;
        f32x16 xlo, xhi;
        asm volatile(
            "s_load_dwordx16 %0, %2, 0x0\n\t"
            "s_load_dwordx16 %1, %2, 0x40\n\t"
            "s_waitcnt lgkmcnt(0)"
            : "=s"(xlo), "=s"(xhi)
            : "s"(xt)
            : "memory");
        __builtin_amdgcn_sched_barrier(0);   // keep uses after the waitcnt

        float v[TGT];
        if (pred == 0) {            // pl=8: 4 distinct patches
            #pragma unroll
            for (int k = 0; k < 4; ++k) {
                float a = 0.f, b = 0.f;
                #pragma unroll
                for (int j = 0; j < 4; ++j) {
                    a = fmaf(r0[j],     XAT(k * 8 + j),     a);
                    b = fmaf(r0[j + 4], XAT(k * 8 + j + 4), b);
                }
                v[k] = a + b;
            }
        } else if (pred == 1) {     // pl=16: repeat idx [0,0,0,1]
            float bt[2];
            #pragma unroll
            for (int kp = 0; kp < 2; ++kp) {
                float a = 0.f, b = 0.f;
                #pragma unroll
                for (int c = 0; c < 2; ++c) {
                    #pragma unroll
                    for (int j = 0; j < 4; ++j) {
                        a = fmaf(r1[c * 8 + j],     XAT(kp * 16 + c * 8 + j),     a);
                        b = fmaf(r1[c * 8 + j + 4], XAT(kp * 16 + c * 8 + j + 4), b);
                    }
                }
                bt[kp] = a + b;
            }
            v[0] = bt[0]; v[1] = bt[0]; v[2] = bt[0]; v[3] = bt[1];
        } else {                    // pl=32: one patch, repeated 4x
            float a = 0.f, b = 0.f;
            #pragma unroll
            for (int c = 0; c < 4; ++c) {
                #pragma unroll
                for (int j = 0; j < 4; ++j) {
                    a = fmaf(r2[c * 8 + j],     XAT(c * 8 + j),     a);
                    b = fmaf(r2[c * 8 + j + 4], XAT(c * 8 + j + 4), b);
                }
            }
            const float av = a + b;
            #pragma unroll
            for (int k = 0; k < 4; ++k) v[k] = av;
        }

        // add PE, rotate per position, nontemporal coalesced stores
        #pragma unroll
        for (int k = 0; k < 4; ++k) {
            __builtin_nontemporal_store(v[k] + pg, obase + k * D_MODEL);
            const float np = fmaf(pg, c1r,  qg * s1l);
            const float nq = fmaf(qg, c1r, -pg * s1l);
            pg = np; qg = nq;
        }
    }
}

// Second tuple output: the scalar C (=21) appended after x_patch.
__global__ void ape_tail(float* p, int n) {
    int i = blockIdx.x * blockDim.x + threadIdx.x;
    if (i < n) p[i] = 21.0f;
}

extern "C" void kernel_launch(void* const* d_in, const int* in_sizes, int n_in,
                              void* d_out, int out_size, void* d_ws, size_t ws_size,
                              hipStream_t stream)
{
    const float* x   = (const float*)d_in[0];
    const float* w1  = (const float*)d_in[1];
    const float* b1  = (const float*)d_in[2];
    const float* w2  = (const float*)d_in[3];
    const float* b2  = (const float*)d_in[4];
    const float* we0 = (const float*)d_in[5];
    const float* we1 = (const float*)d_in[6];
    const float* we2 = (const float*)d_in[7];
    float* out = (float*)d_out;
    int* preds = (int*)d_ws;                                // 43008 ints = 172 KB

    const long long NR = (long long)in_sizes[0] / MAX_PL;   // B*C*R = 43008

    ape_preds<<<(int)(NR / P_TILES), NTHREADS, 0, stream>>>(x, w1, b1, w2, b2, preds);

    const int nblocks = (int)(NR / G_TILES) * 2;            // 2688 half-blocks
    ape_embed<<<nblocks, NTHREADS, 0, stream>>>(x, preds, we0, we1, we2, out);

    const long long main_elems = NR * (long long)(TGT * D_MODEL);
    if ((long long)out_size > main_elems) {
        const int tail = (int)((long long)out_size - main_elems);
        ape_tail<<<(tail + 63) / 64, 64, 0, stream>>>(out + main_elems, tail);
    }
}